// Round 9
// baseline (1320.211 us; speedup 1.0000x reference)
//
#include <hip/hip_runtime.h>
#include <hip/hip_bf16.h>

typedef unsigned short u16;
typedef short bf16x8 __attribute__((ext_vector_type(8)));
typedef float f32x4 __attribute__((ext_vector_type(4)));
typedef unsigned short u16x8 __attribute__((ext_vector_type(8)));

#define PD 147

static const long OFF_PREAL = 134217728L;
static const long OFF_PRECON= 135421952L;
static const long OFF_WA    = 136626176L;
static const long OFF_WP    = 138723328L;

// raw f4 bf16 NHWC split: elems [0,100663296) (= batches 0..5) at d_out
// u16-offset 167772160 (top 201.3MB of feat region); batches 6,7 in ws f2
// region (exactly 64 MiB).
static const long RAW_SPLIT = 100663296L;

__device__ __forceinline__ float lrelu(float v){ return v >= 0.f ? v : 0.01f*v; }

__device__ __forceinline__ float bf2f(u16 u){
    union { unsigned int i; float f; } x; x.i = ((unsigned int)u) << 16; return x.f;
}
__device__ __forceinline__ u16 f2bf(float f){
    __hip_bfloat16 h = __float2bfloat16(f);
    return *reinterpret_cast<u16*>(&h);
}

__device__ __forceinline__ void gload16(const void* g, void* l){
    __builtin_amdgcn_global_load_lds((const __attribute__((address_space(1))) void*)g,
                                     (__attribute__((address_space(3))) void*)l, 16, 0, 0);
}

// ---------------------------------------------------------------------------
// MFMA implicit-GEMM 3x3 SAME conv.  16x16 spatial tile x all K_OUT channels
// per block.  8 waves (2M x 4N).  Input NHWC bf16 (pre-activated), weights
// pre-transposed [tap][k_out][c_in] bf16.  BK=96 steps (one dy-row = 3 taps
// per step).  Round-4/8 proven single-barrier skeleton.
//
// CRITICAL (guide §5, m104/m108): gload16's LDS destination must be the
// WAVE-UNIFORM base (HW adds lane*16B); per-lane dst + masked exec shifts
// the whole wave's rows (round-7 bug).
// Output: NHWC bf16 raw (all layers).  SPLIT: batches 0..5 -> out_, 6,7 ->
// rawhi (b-uniform per block).  Fused deterministic BN partial stats.
// ---------------------------------------------------------------------------
template<int CIN, int KOUT, bool SPLIT>
__global__ __launch_bounds__(512)
void conv_mfma(const u16* __restrict__ fin, const u16* __restrict__ wt,
               void* __restrict__ out_, u16* __restrict__ rawhi,
               float* __restrict__ part)
{
    constexpr int CC = CIN / 32;
    constexpr int NS3 = CC * 3;                        // dy-row steps
    constexpr int NF = KOUT / 64;
    constexpr int ABYTES = 2 * 324 * 32 * 2;           // dbuf 18x18x32 bf16
    constexpr int BQ = 3 * KOUT * 4;                   // quarters per B buffer
    constexpr int NB3 = (BQ + 511) / 512;              // stage_b rounds
    constexpr int BBYTES = 2 * BQ * 16;
    constexpr int EPIB = 256 * KOUT * 2;
    constexpr int SB = (ABYTES + BBYTES) > EPIB ? (ABYTES + BBYTES) : EPIB;
    __shared__ __align__(16) char smem[SB];
    u16* As = (u16*)smem;
    u16* Bs = (u16*)(smem + ABYTES);

    const int tid = threadIdx.x;
    const int w = tid >> 6, lane = tid & 63;
    const int wm = w >> 2, wn = w & 3;
    const int tile = blockIdx.x;
    const int tx0 = (tile & 15) << 4, ty0 = (tile >> 4) << 4;
    const int b = blockIdx.y;
    const long pixbase = (long)b << 16;
    const int hi = lane >> 4;

    f32x4 acc[8][NF];
#pragma unroll
    for (int m = 0; m < 8; m++)
#pragma unroll
        for (int n = 0; n < NF; n++) acc[m][n] = (f32x4){0.f,0.f,0.f,0.f};

    // zero both A buffers once (halo cells never written -> stay zero)
    for (int i = tid; i < ABYTES/16; i += 512)
        ((int4*)smem)[i] = make_int4(0,0,0,0);
    __syncthreads();

    auto stage_a_round = [&](int cc, int buf, int r){
        u16* dstbase = As + buf * (324*32);
        int q = r*512 + w*64 + lane;
        int pf = q >> 2, quarter = q & 3;
        int ly = pf / 18;
        int lx = pf - ly*18;
        int gy = ty0 + ly - 1, gx = tx0 + lx - 1;
        bool ok = (q < 1296) && ((unsigned)gy < 256u) && ((unsigned)gx < 256u);
        const u16* src = fin + ((pixbase + (gy<<8) + gx) * CIN + cc*32 + quarter*8);
        u16* dst = dstbase + (r*512 + w*64) * 8;   // WAVE-UNIFORM base
        if (ok) gload16(src, dst);
    };
    auto stage_b3 = [&](int s, int buf){
        int cc = s / 3, dyr = s - cc*3;
        int t0 = dyr * 3;
        u16* dstbase = Bs + buf * (BQ*16/2);
#pragma unroll
        for (int r = 0; r < NB3; ++r){
            int q = r*512 + w*64 + lane;
            int tl = q / (KOUT*4);
            int qq = q - tl*(KOUT*4);
            int k = qq >> 2, quarter = qq & 3;
            const u16* src = wt + (((long)(t0+tl)*KOUT + k) * CIN + cc*32 + quarter*8);
            u16* dst = dstbase + (r*512 + w*64) * 8;   // WAVE-UNIFORM base
            if (q < BQ) gload16(src, dst);
        }
    };

    // prologue
    stage_a_round(0, 0, 0); stage_a_round(0, 0, 1); stage_a_round(0, 0, 2);
    stage_b3(0, 0);
    __syncthreads();

#pragma unroll 1
    for (int s = 0; s < NS3; ++s){
        int cc = s / 3, dyr = s - cc*3;
        if (s + 1 < NS3) stage_b3(s + 1, (s + 1) & 1);
        if (cc + 1 < CC) stage_a_round(cc + 1, (cc + 1) & 1, dyr);

        const u16* Ab = As + (cc & 1) * (324*32);
        const u16* Bb = Bs + (s & 1) * (BQ*16/2);
#pragma unroll
        for (int t = 0; t < 3; ++t){
            bf16x8 av[8];
#pragma unroll
            for (int m = 0; m < 8; m++){
                int pf = (wm*8 + m + dyr)*18 + (lane & 15) + t;
                av[m] = *(const bf16x8*)(Ab + pf*32 + hi*8);
            }
            bf16x8 bv[NF];
#pragma unroll
            for (int n = 0; n < NF; n++){
                int ch = (wn*NF + n)*16 + (lane & 15);
                bv[n] = *(const bf16x8*)(Bb + (t*KOUT + ch)*32 + hi*8);
            }
#pragma unroll
            for (int m = 0; m < 8; m++)
#pragma unroll
                for (int n = 0; n < NF; n++)
                    acc[m][n] = __builtin_amdgcn_mfma_f32_16x16x32_bf16(av[m], bv[n], acc[m][n], 0, 0, 0);
        }
        __syncthreads();   // drains vmcnt (next bufs ready) + readers done
    }

    // ---- fused BN partial stats (fp32, pre-rounding), deterministic slots ----
    {
        const int bid = blockIdx.y * 256 + blockIdx.x;
        const long slot = (long)bid * 2 + wm;
#pragma unroll
        for (int n = 0; n < NF; n++){
            float s = 0.f, s2 = 0.f;
#pragma unroll
            for (int m = 0; m < 8; m++)
#pragma unroll
                for (int j = 0; j < 4; j++){
                    float v = acc[m][n][j];
                    s += v; s2 += v*v;
                }
            s += __shfl_down(s, 32); s2 += __shfl_down(s2, 32);
            s += __shfl_down(s, 16); s2 += __shfl_down(s2, 16);
            if (lane < 16){
                int ch = (wn*NF + n)*16 + lane;
                long off = (slot*KOUT + ch)*2;
                part[off]   = s;
                part[off+1] = s2;
            }
        }
    }

    // block-wide LDS transpose -> NHWC bf16 raw, fully coalesced stores
    {
        u16* ep = (u16*)smem;
        u16* outh = (u16*)out_;
        if (SPLIT && b >= 6) outh = rawhi - RAW_SPLIT;
#pragma unroll
        for (int m = 0; m < 8; m++)
#pragma unroll
            for (int n = 0; n < NF; n++){
                int ch = (wn*NF + n)*16 + (lane&15);
#pragma unroll
                for (int j = 0; j < 4; j++){
                    int px = wm*128 + m*16 + (lane>>4)*4 + j;
                    ep[px*KOUT + ch] = f2bf(acc[m][n][j]);
                }
            }
        __syncthreads();
        const int n16 = 256*KOUT/8;
        const int upr = KOUT*2;                 // 16B units per spatial row
        for (int i = tid; i < n16; i += 512){
            int py = i / upr;
            int rem = i - py*upr;
            long ga = (pixbase + ((ty0+py)<<8) + tx0) * KOUT + (long)rem*8;
            *(int4*)(outh + ga) = *(int4*)(ep + (long)i*8);
        }
    }
}

// ---------------------------------------------------------------------------
// conv1: 3->32 direct (tiny), output NHWC bf16 raw
// ---------------------------------------------------------------------------
__global__ __launch_bounds__(256)
void conv1_direct(const float* __restrict__ x, const float* __restrict__ w1, u16* __restrict__ f1)
{
    __shared__ float wl[864];
    const int t = threadIdx.x;
    for (int i = t; i < 864; i += 256) wl[i] = w1[i];
    __syncthreads();
    const int y = blockIdx.x, b = blockIdx.y;
    float acc[32];
#pragma unroll
    for (int k = 0; k < 32; k++) acc[k] = 0.f;
    const long ib = (long)b*3*65536;
    for (int c = 0; c < 3; c++){
#pragma unroll
        for (int dy = 0; dy < 3; dy++){
            int gy = y + dy - 1;
#pragma unroll
            for (int dx = 0; dx < 3; dx++){
                int gx = t + dx - 1;
                float v = 0.f;
                if ((unsigned)gy < 256u && (unsigned)gx < 256u)
                    v = x[ib + c*65536 + (gy<<8) + gx];
                const float* wp = &wl[c*9 + dy*3 + dx];
#pragma unroll
                for (int k = 0; k < 32; k++) acc[k] += v * wp[k*27];
            }
        }
    }
    u16 ub[32];
#pragma unroll
    for (int k = 0; k < 32; k++) ub[k] = f2bf(acc[k]);
    u16* dst = f1 + ((long)(b*65536 + (y<<8) + t)) * 32;
#pragma unroll
    for (int j = 0; j < 4; j++) *(int4*)(dst + j*8) = *(int4*)(ub + j*8);
}

// weight transpose: wt[tap][k][c] = bf16(w[k][c][tap])
__global__ __launch_bounds__(256)
void prep_w(const float* __restrict__ w, u16* __restrict__ wt, int K, int C)
{
    int i = blockIdx.x*256 + threadIdx.x;
    if (i >= 9*K*C) return;
    int c = i % C; int r = i / C; int k = r % K; int tap = r / K;
    wt[i] = f2bf(w[((long)k*C + c)*9 + tap]);
}

// ---------------------------------------------------------------------------
// BN stats over NHWC bf16 (layer 1 only)
// ---------------------------------------------------------------------------
template<int C>
__global__ __launch_bounds__(256)
void bn_stats_nhwc(const u16* __restrict__ f, float* __restrict__ part)
{
    constexpr int CQ = C/4;
    constexpr int SUBS = 256/CQ;
    const int t = threadIdx.x;
    const int cq = t & (CQ-1);
    const int sub = t / CQ;
    const long rowbase = (long)blockIdx.x * 512;
    float s[4] = {0,0,0,0}, q2[4] = {0,0,0,0};
    for (int r = sub; r < 512; r += SUBS){
        ushort4 v = *(const ushort4*)(f + (rowbase + r)*C + cq*4);
        float x0 = bf2f(v.x), x1 = bf2f(v.y), x2 = bf2f(v.z), x3 = bf2f(v.w);
        s[0]+=x0; q2[0]+=x0*x0; s[1]+=x1; q2[1]+=x1*x1;
        s[2]+=x2; q2[2]+=x2*x2; s[3]+=x3; q2[3]+=x3*x3;
    }
    __shared__ float r0[256], r1[256];
    for (int j = 0; j < 4; j++){
        r0[t] = s[j]; r1[t] = q2[j];
        __syncthreads();
        for (int st = 128; st >= CQ; st >>= 1){
            if (t < st){ r0[t] += r0[t+st]; r1[t] += r1[t+st]; }
            __syncthreads();
        }
        if (t < CQ){
            part[((long)blockIdx.x * C + t*4 + j)*2]     = r0[t];
            part[((long)blockIdx.x * C + t*4 + j)*2 + 1] = r1[t];
        }
        __syncthreads();
    }
}

__global__ __launch_bounds__(256)
void bn_stats_final2(const float* __restrict__ part, const float* __restrict__ g,
                     const float* __restrict__ bb, int C, int NB2, float* __restrict__ ss)
{
    const int c = blockIdx.x, t = threadIdx.x;
    float s = 0.f, s2 = 0.f;
    for (int i = t; i < NB2; i += 256){
        s  += part[((long)i*C + c)*2];
        s2 += part[((long)i*C + c)*2 + 1];
    }
    __shared__ float r0[256], r1[256];
    r0[t] = s; r1[t] = s2;
    __syncthreads();
    for (int st = 128; st > 0; st >>= 1){
        if (t < st){ r0[t] += r0[t+st]; r1[t] += r1[t+st]; }
        __syncthreads();
    }
    if (t == 0){
        const float invN = 1.f/524288.f;
        float m = r0[0]*invN;
        float v = r1[0]*invN - m*m;
        float sc = g[c]/sqrtf(v + 1e-5f);
        ss[c] = sc; ss[C+c] = bb[c] - m*sc;
    }
}

// apply BN+lrelu in place on NHWC bf16 (f1,f2,f3)
template<int C>
__global__ __launch_bounds__(256)
void bn_apply(u16* __restrict__ f, const float* __restrict__ ss, long n8)
{
    long i = (long)blockIdx.x*256 + threadIdx.x;
    if (i >= n8) return;
    u16x8 v = *(u16x8*)(f + i*8);
    int c0 = (int)((i*8) & (C-1));
#pragma unroll
    for (int j = 0; j < 8; j++){
        float xx = bf2f(v[j]);
        xx = lrelu(ss[c0+j]*xx + ss[C+c0+j]);
        v[j] = f2bf(xx);
    }
    *(u16x8*)(f + i*8) = v;
}

// ---------------------------------------------------------------------------
// f4 raw NHWC bf16 -> NCHW fp32 feat with BN+lrelu (LDS-tiled transpose).
// Block = (b, y, half): reads 128 px x 256 ch contiguous, writes 128-float
// runs per channel.  lds padded [128][258] -> conflict-free column reads.
// ---------------------------------------------------------------------------
__global__ __launch_bounds__(256)
void bn_expand_t(const u16* __restrict__ rawlo, const u16* __restrict__ rawhi,
                 const float* __restrict__ ss, float* __restrict__ feat, int b0)
{
    __shared__ u16 lds[128*258];
    const int bid = blockIdx.x;
    const int b = b0 + (bid >> 9);
    const int y = (bid >> 1) & 255;
    const int half = bid & 1;
    const long p0 = ((long)((b<<16) + (y<<8) + half*128)) << 8;
    const u16* src = (b < 6) ? (rawlo + p0) : (rawhi + (p0 - RAW_SPLIT));
    const int t = threadIdx.x;
#pragma unroll
    for (int it = 0; it < 16; ++it){
        int i = it*256 + t;
        int px = i >> 5, u = i & 31;
        *(u16x8*)&lds[px*258 + u*8] = *(const u16x8*)(src + (long)i*8);
    }
    __syncthreads();
    const int c = t;
    const float sc = ss[c], sh = ss[256 + c];
    float* fb = feat + (((long)(b*256 + c)) << 16) + y*256 + half*128;
#pragma unroll 4
    for (int j = 0; j < 32; ++j){
        float4 o;
        o.x = lrelu(sc*bf2f(lds[(j*4+0)*258 + c]) + sh);
        o.y = lrelu(sc*bf2f(lds[(j*4+1)*258 + c]) + sh);
        o.z = lrelu(sc*bf2f(lds[(j*4+2)*258 + c]) + sh);
        o.w = lrelu(sc*bf2f(lds[(j*4+3)*258 + c]) + sh);
        *(float4*)(fb + j*4) = o;
    }
}

// ---------------------------------------------------------------------------
// gather W from raw NHWC bf16 + inline BN (same arithmetic as bn_expand_t,
// so results match feat exactly).  One contiguous 512B read per site.
// ---------------------------------------------------------------------------
__global__ __launch_bounds__(256)
void gather_w_raw(const u16* __restrict__ rawlo, const u16* __restrict__ rawhi,
                  const float* __restrict__ ss, const int* __restrict__ hw,
                  float* __restrict__ outW)
{
    const int site = blockIdx.x;
    const int b = site >> 10;
    const int y = hw[site*2], x = hw[site*2 + 1];
    const int c = threadIdx.x;
    const long p = ((long)((b<<16) + (y<<8) + x)) << 8;
    const u16* base = (b < 6) ? (rawlo + p) : (rawhi + (p - RAW_SPLIT));
    float v = bf2f(base[c]);
    outW[(long)site*256 + c] = lrelu(ss[c]*v + ss[256 + c]);
}

__global__ __launch_bounds__(256)
void gather_patch(const float* __restrict__ x, const int* __restrict__ hw,
                  float* __restrict__ out)
{
    const long i = (long)blockIdx.x*256 + threadIdx.x;
    if (i >= 1204224L) return;
    const int px = (int)(i % 7);
    long r = i / 7;
    const int py = (int)(r % 7); r /= 7;
    const int c  = (int)(r % 3); r /= 3;
    const int s  = (int)(r % 1024);
    const int b  = (int)(r / 1024);
    const int site = b*1024 + s;
    const int yy = hw[site*2]     - 3 + py;
    const int xx = hw[site*2 + 1] - 3 + px;
    out[i] = x[(((long)(b*3 + c)) << 16) + ((long)yy << 8) + xx];
}

// ---------------------------------------------------------------------------
// decoder MLP, 8 sites per block (8x weight reuse per load)
// ---------------------------------------------------------------------------
__global__ __launch_bounds__(256)
void mlp8(const float* __restrict__ Wa, const float* __restrict__ l1w,
          const float* __restrict__ l1b, const float* __restrict__ l2w,
          const float* __restrict__ l2b, float* __restrict__ out)
{
    __shared__ float wa[2048];
    __shared__ float h[8][152];
    const int blk = blockIdx.x;
    const int t = threadIdx.x;
#pragma unroll
    for (int it = 0; it < 8; ++it)
        wa[it*256 + t] = Wa[(long)blk*2048 + it*256 + t];
    __syncthreads();
    if (t < PD){
        float a[8] = {0,0,0,0,0,0,0,0};
        const float* wr = l1w + t*256;
#pragma unroll 4
        for (int l = 0; l < 256; ++l){
            float wv = wr[l];
#pragma unroll
            for (int g = 0; g < 8; ++g) a[g] += wa[g*256 + l]*wv;
        }
        float bb = l1b[t];
#pragma unroll
        for (int g = 0; g < 8; ++g) h[g][t] = lrelu(a[g] + bb);
    }
    __syncthreads();
    if (t < PD){
        float r[8] = {0,0,0,0,0,0,0,0};
        const float* wr = l2w + t*PD;
        for (int p = 0; p < PD; ++p){
            float wv = wr[p];
#pragma unroll
            for (int g = 0; g < 8; ++g) r[g] += h[g][p]*wv;
        }
        float bb = l2b[t];
#pragma unroll
        for (int g = 0; g < 8; ++g)
            out[((long)(blk*8 + g))*PD + t] = r[g] + bb;
    }
}

extern "C" void kernel_launch(void* const* d_in, const int* in_sizes, int n_in,
                              void* d_out, int out_size, void* d_ws, size_t ws_size,
                              hipStream_t stream)
{
    const float* x   = (const float*)d_in[0];
    const int*   anc = (const int*)  d_in[1];
    const int*   pos = (const int*)  d_in[2];
    const float* w1  = (const float*)d_in[3];
    const float* g1  = (const float*)d_in[4];
    const float* b1  = (const float*)d_in[5];
    const float* w2  = (const float*)d_in[6];
    const float* g2  = (const float*)d_in[7];
    const float* b2  = (const float*)d_in[8];
    const float* w3  = (const float*)d_in[9];
    const float* g3  = (const float*)d_in[10];
    const float* b3  = (const float*)d_in[11];
    const float* w4  = (const float*)d_in[12];
    const float* g4  = (const float*)d_in[13];
    const float* b4  = (const float*)d_in[14];
    const float* l1w = (const float*)d_in[15];
    const float* l1b = (const float*)d_in[16];
    const float* l2w = (const float*)d_in[17];
    const float* l2b = (const float*)d_in[18];

    float* feat = (float*)d_out;
    float* oPR  = feat + OFF_PREAL;
    float* oRC  = feat + OFF_PRECON;
    float* oWA  = feat + OFF_WA;
    float* oWP  = feat + OFF_WP;

    // ws: f2 [0,64MB), f3 [64MB,192MB), f1 [128MB,160MB) (inside f3, dead before conv3)
    char* wsb = (char*)d_ws;
    u16* f2b = (u16*)wsb;
    u16* f3b = (u16*)(wsb + 67108864L);
    u16* f1b = (u16*)(wsb + 134217728L);

    // raw f4 bf16 NHWC: batches 0..5 in top of feat region; 6,7 in f2 region
    u16* rawlo = (u16*)d_out + 167772160L;    // byte offset 335544320
    u16* rawhi = f2b;                          // f2 dead after conv3

    // scratch inside d_out regions only written by later kernels
    u16* Wt2 = (u16*)oWA;                      // dead after conv2
    u16* Wt3 = Wt2 + 18432;                    // dead after conv3
    u16* Wt4 = Wt3 + 73728;                    // dead after conv4
    float* part = oWP;                         // dead after stats_final; gather_w(pos) overwrites
    float* ss1 = oRC, *ss2 = oRC + 64, *ss3 = oRC + 192, *ss4 = oRC + 448;  // dead before mlp8

    prep_w<<<72,   256, 0, stream>>>(w2, Wt2, 64, 32);
    prep_w<<<288,  256, 0, stream>>>(w3, Wt3, 128, 64);
    prep_w<<<1152, 256, 0, stream>>>(w4, Wt4, 256, 128);

    conv1_direct<<<dim3(256,8), 256, 0, stream>>>(x, w1, f1b);
    bn_stats_nhwc<32><<<1024, 256, 0, stream>>>(f1b, part);
    bn_stats_final2<<<32, 256, 0, stream>>>(part, g1, b1, 32, 1024, ss1);
    bn_apply<32><<<8192, 256, 0, stream>>>(f1b, ss1, 2097152L);

    conv_mfma<32,64,false><<<dim3(256,8), 512, 0, stream>>>(f1b, Wt2, f2b, nullptr, part);
    bn_stats_final2<<<64, 256, 0, stream>>>(part, g2, b2, 64, 4096, ss2);
    bn_apply<64><<<16384, 256, 0, stream>>>(f2b, ss2, 4194304L);

    conv_mfma<64,128,false><<<dim3(256,8), 512, 0, stream>>>(f2b, Wt3, f3b, nullptr, part);
    bn_stats_final2<<<128, 256, 0, stream>>>(part, g3, b3, 128, 4096, ss3);
    bn_apply<128><<<32768, 256, 0, stream>>>(f3b, ss3, 8388608L);

    conv_mfma<128,256,true><<<dim3(256,8), 512, 0, stream>>>(f3b, Wt4, rawlo, rawhi, part);
    bn_stats_final2<<<256, 256, 0, stream>>>(part, g4, b4, 256, 4096, ss4);

    // gathers read RAW f4 (+inline BN, identical arithmetic to expand) BEFORE
    // the expand kernels clobber the raw regions.
    gather_w_raw<<<8192, 256, 0, stream>>>(rawlo, rawhi, ss4, anc, oWA);
    gather_w_raw<<<8192, 256, 0, stream>>>(rawlo, rawhi, ss4, pos, oWP);
    gather_patch<<<4704, 256, 0, stream>>>(x, anc, oPR);

    // expand raw -> fp32 feat (transpose).  Safety by launch order:
    //  E1: b 0..4  writes feat bytes [0, 335.5MB)       (below rawlo)
    //  E2: b 5     writes [335.5, 402.7) = raw of b0,b1 (read by E1)
    //  E3: b 6,7   reads ws, writes [402.7, 537) = raw of b2..b5 (read E1/E2)
    bn_expand_t<<<2560, 256, 0, stream>>>(rawlo, rawhi, ss4, feat, 0);
    bn_expand_t<<<512,  256, 0, stream>>>(rawlo, rawhi, ss4, feat, 5);
    bn_expand_t<<<1024, 256, 0, stream>>>(rawlo, rawhi, ss4, feat, 6);

    // mlp last: it overwrites oRC (incl. ss slots) after all consumers done
    mlp8<<<1024, 256, 0, stream>>>(oWA, l1w, l1b, l2w, l2b, oRC);
}

// Round 10
// 824.018 us; speedup vs baseline: 1.6022x; 1.6022x over previous
//
#include <hip/hip_runtime.h>
#include <hip/hip_bf16.h>

typedef unsigned short u16;
typedef short bf16x8 __attribute__((ext_vector_type(8)));
typedef float f32x4 __attribute__((ext_vector_type(4)));
typedef unsigned short u16x8 __attribute__((ext_vector_type(8)));

#define PD 147

static const long OFF_PREAL = 134217728L;
static const long OFF_PRECON= 135421952L;
static const long OFF_WA    = 136626176L;
static const long OFF_WP    = 138723328L;

// raw f4 bf16 NHWC split: elems [0,100663296) (= batches 0..5) at d_out
// u16-offset 167772160 (top 201.3MB of feat region); batches 6,7 in ws f2
// region (exactly 64 MiB).
static const long RAW_SPLIT = 100663296L;

__device__ __forceinline__ float lrelu(float v){ return v >= 0.f ? v : 0.01f*v; }

__device__ __forceinline__ float bf2f(u16 u){
    union { unsigned int i; float f; } x; x.i = ((unsigned int)u) << 16; return x.f;
}
__device__ __forceinline__ u16 f2bf(float f){
    __hip_bfloat16 h = __float2bfloat16(f);
    return *reinterpret_cast<u16*>(&h);
}

__device__ __forceinline__ void gload16(const void* g, void* l){
    __builtin_amdgcn_global_load_lds((const __attribute__((address_space(1))) void*)g,
                                     (__attribute__((address_space(3))) void*)l, 16, 0, 0);
}

// ---------------------------------------------------------------------------
// MFMA implicit-GEMM 3x3 SAME conv.  16x16 spatial tile x all K_OUT channels
// per block.  8 waves (2M x 4N).  Input NHWC bf16 (pre-activated), weights
// pre-transposed [tap][k_out][c_in] bf16.  BK=96 steps (one dy-row = 3 taps
// per step).  Round-4/8 proven single-barrier skeleton.
//
// CRITICAL (guide §5, m104/m108): gload16's LDS destination must be the
// WAVE-UNIFORM base (HW adds lane*16B); per-lane dst + masked exec shifts
// the whole wave's rows (round-7 bug).
// Output: NHWC bf16 raw (all layers).  SPLIT: batches 0..5 -> out_, 6,7 ->
// rawhi (b-uniform per block).  Fused deterministic BN partial stats.
// ---------------------------------------------------------------------------
template<int CIN, int KOUT, bool SPLIT>
__global__ __launch_bounds__(512)
void conv_mfma(const u16* __restrict__ fin, const u16* __restrict__ wt,
               void* __restrict__ out_, u16* __restrict__ rawhi,
               float* __restrict__ part)
{
    constexpr int CC = CIN / 32;
    constexpr int NS3 = CC * 3;                        // dy-row steps
    constexpr int NF = KOUT / 64;
    constexpr int ABYTES = 2 * 324 * 32 * 2;           // dbuf 18x18x32 bf16
    constexpr int BQ = 3 * KOUT * 4;                   // quarters per B buffer
    constexpr int NB3 = (BQ + 511) / 512;              // stage_b rounds
    constexpr int BBYTES = 2 * BQ * 16;
    constexpr int EPIB = 256 * KOUT * 2;
    constexpr int SB = (ABYTES + BBYTES) > EPIB ? (ABYTES + BBYTES) : EPIB;
    __shared__ __align__(16) char smem[SB];
    u16* As = (u16*)smem;
    u16* Bs = (u16*)(smem + ABYTES);

    const int tid = threadIdx.x;
    const int w = tid >> 6, lane = tid & 63;
    const int wm = w >> 2, wn = w & 3;
    const int tile = blockIdx.x;
    const int tx0 = (tile & 15) << 4, ty0 = (tile >> 4) << 4;
    const int b = blockIdx.y;
    const long pixbase = (long)b << 16;
    const int hi = lane >> 4;

    f32x4 acc[8][NF];
#pragma unroll
    for (int m = 0; m < 8; m++)
#pragma unroll
        for (int n = 0; n < NF; n++) acc[m][n] = (f32x4){0.f,0.f,0.f,0.f};

    // zero both A buffers once (halo cells never written -> stay zero)
    for (int i = tid; i < ABYTES/16; i += 512)
        ((int4*)smem)[i] = make_int4(0,0,0,0);
    __syncthreads();

    auto stage_a_round = [&](int cc, int buf, int r){
        u16* dstbase = As + buf * (324*32);
        int q = r*512 + w*64 + lane;
        int pf = q >> 2, quarter = q & 3;
        int ly = pf / 18;
        int lx = pf - ly*18;
        int gy = ty0 + ly - 1, gx = tx0 + lx - 1;
        bool ok = (q < 1296) && ((unsigned)gy < 256u) && ((unsigned)gx < 256u);
        const u16* src = fin + ((pixbase + (gy<<8) + gx) * CIN + cc*32 + quarter*8);
        u16* dst = dstbase + (r*512 + w*64) * 8;   // WAVE-UNIFORM base
        if (ok) gload16(src, dst);
    };
    auto stage_b3 = [&](int s, int buf){
        int cc = s / 3, dyr = s - cc*3;
        int t0 = dyr * 3;
        u16* dstbase = Bs + buf * (BQ*16/2);
#pragma unroll
        for (int r = 0; r < NB3; ++r){
            int q = r*512 + w*64 + lane;
            int tl = q / (KOUT*4);
            int qq = q - tl*(KOUT*4);
            int k = qq >> 2, quarter = qq & 3;
            const u16* src = wt + (((long)(t0+tl)*KOUT + k) * CIN + cc*32 + quarter*8);
            u16* dst = dstbase + (r*512 + w*64) * 8;   // WAVE-UNIFORM base
            if (q < BQ) gload16(src, dst);
        }
    };

    // prologue
    stage_a_round(0, 0, 0); stage_a_round(0, 0, 1); stage_a_round(0, 0, 2);
    stage_b3(0, 0);
    __syncthreads();

#pragma unroll 1
    for (int s = 0; s < NS3; ++s){
        int cc = s / 3, dyr = s - cc*3;
        if (s + 1 < NS3) stage_b3(s + 1, (s + 1) & 1);
        if (cc + 1 < CC) stage_a_round(cc + 1, (cc + 1) & 1, dyr);

        const u16* Ab = As + (cc & 1) * (324*32);
        const u16* Bb = Bs + (s & 1) * (BQ*16/2);
#pragma unroll
        for (int t = 0; t < 3; ++t){
            bf16x8 av[8];
#pragma unroll
            for (int m = 0; m < 8; m++){
                int pf = (wm*8 + m + dyr)*18 + (lane & 15) + t;
                av[m] = *(const bf16x8*)(Ab + pf*32 + hi*8);
            }
            bf16x8 bv[NF];
#pragma unroll
            for (int n = 0; n < NF; n++){
                int ch = (wn*NF + n)*16 + (lane & 15);
                bv[n] = *(const bf16x8*)(Bb + (t*KOUT + ch)*32 + hi*8);
            }
#pragma unroll
            for (int m = 0; m < 8; m++)
#pragma unroll
                for (int n = 0; n < NF; n++)
                    acc[m][n] = __builtin_amdgcn_mfma_f32_16x16x32_bf16(av[m], bv[n], acc[m][n], 0, 0, 0);
        }
        __syncthreads();   // drains vmcnt (next bufs ready) + readers done
    }

    // ---- fused BN partial stats (fp32, pre-rounding), deterministic slots ----
    {
        const int bid = blockIdx.y * 256 + blockIdx.x;
        const long slot = (long)bid * 2 + wm;
#pragma unroll
        for (int n = 0; n < NF; n++){
            float s = 0.f, s2 = 0.f;
#pragma unroll
            for (int m = 0; m < 8; m++)
#pragma unroll
                for (int j = 0; j < 4; j++){
                    float v = acc[m][n][j];
                    s += v; s2 += v*v;
                }
            s += __shfl_down(s, 32); s2 += __shfl_down(s2, 32);
            s += __shfl_down(s, 16); s2 += __shfl_down(s2, 16);
            if (lane < 16){
                int ch = (wn*NF + n)*16 + lane;
                long off = (slot*KOUT + ch)*2;
                part[off]   = s;
                part[off+1] = s2;
            }
        }
    }

    // block-wide LDS transpose -> NHWC bf16 raw, fully coalesced stores
    {
        u16* ep = (u16*)smem;
        u16* outh = (u16*)out_;
        if (SPLIT && b >= 6) outh = rawhi - RAW_SPLIT;
#pragma unroll
        for (int m = 0; m < 8; m++)
#pragma unroll
            for (int n = 0; n < NF; n++){
                int ch = (wn*NF + n)*16 + (lane&15);
#pragma unroll
                for (int j = 0; j < 4; j++){
                    int px = wm*128 + m*16 + (lane>>4)*4 + j;
                    ep[px*KOUT + ch] = f2bf(acc[m][n][j]);
                }
            }
        __syncthreads();
        const int n16 = 256*KOUT/8;
        const int upr = KOUT*2;                 // 16B units per spatial row
        for (int i = tid; i < n16; i += 512){
            int py = i / upr;
            int rem = i - py*upr;
            long ga = (pixbase + ((ty0+py)<<8) + tx0) * KOUT + (long)rem*8;
            *(int4*)(outh + ga) = *(int4*)(ep + (long)i*8);
        }
    }
}

// ---------------------------------------------------------------------------
// conv1: 3->32 direct (tiny), output NHWC bf16 raw
// ---------------------------------------------------------------------------
__global__ __launch_bounds__(256)
void conv1_direct(const float* __restrict__ x, const float* __restrict__ w1, u16* __restrict__ f1)
{
    __shared__ float wl[864];
    const int t = threadIdx.x;
    for (int i = t; i < 864; i += 256) wl[i] = w1[i];
    __syncthreads();
    const int y = blockIdx.x, b = blockIdx.y;
    float acc[32];
#pragma unroll
    for (int k = 0; k < 32; k++) acc[k] = 0.f;
    const long ib = (long)b*3*65536;
    for (int c = 0; c < 3; c++){
#pragma unroll
        for (int dy = 0; dy < 3; dy++){
            int gy = y + dy - 1;
#pragma unroll
            for (int dx = 0; dx < 3; dx++){
                int gx = t + dx - 1;
                float v = 0.f;
                if ((unsigned)gy < 256u && (unsigned)gx < 256u)
                    v = x[ib + c*65536 + (gy<<8) + gx];
                const float* wp = &wl[c*9 + dy*3 + dx];
#pragma unroll
                for (int k = 0; k < 32; k++) acc[k] += v * wp[k*27];
            }
        }
    }
    u16 ub[32];
#pragma unroll
    for (int k = 0; k < 32; k++) ub[k] = f2bf(acc[k]);
    u16* dst = f1 + ((long)(b*65536 + (y<<8) + t)) * 32;
#pragma unroll
    for (int j = 0; j < 4; j++) *(int4*)(dst + j*8) = *(int4*)(ub + j*8);
}

// weight transpose: wt[tap][k][c] = bf16(w[k][c][tap])
__global__ __launch_bounds__(256)
void prep_w(const float* __restrict__ w, u16* __restrict__ wt, int K, int C)
{
    int i = blockIdx.x*256 + threadIdx.x;
    if (i >= 9*K*C) return;
    int c = i % C; int r = i / C; int k = r % K; int tap = r / K;
    wt[i] = f2bf(w[((long)k*C + c)*9 + tap]);
}

// ---------------------------------------------------------------------------
// BN stats over NHWC bf16 (layer 1 only)
// ---------------------------------------------------------------------------
template<int C>
__global__ __launch_bounds__(256)
void bn_stats_nhwc(const u16* __restrict__ f, float* __restrict__ part)
{
    constexpr int CQ = C/4;
    constexpr int SUBS = 256/CQ;
    const int t = threadIdx.x;
    const int cq = t & (CQ-1);
    const int sub = t / CQ;
    const long rowbase = (long)blockIdx.x * 512;
    float s[4] = {0,0,0,0}, q2[4] = {0,0,0,0};
    for (int r = sub; r < 512; r += SUBS){
        ushort4 v = *(const ushort4*)(f + (rowbase + r)*C + cq*4);
        float x0 = bf2f(v.x), x1 = bf2f(v.y), x2 = bf2f(v.z), x3 = bf2f(v.w);
        s[0]+=x0; q2[0]+=x0*x0; s[1]+=x1; q2[1]+=x1*x1;
        s[2]+=x2; q2[2]+=x2*x2; s[3]+=x3; q2[3]+=x3*x3;
    }
    __shared__ float r0[256], r1[256];
    for (int j = 0; j < 4; j++){
        r0[t] = s[j]; r1[t] = q2[j];
        __syncthreads();
        for (int st = 128; st >= CQ; st >>= 1){
            if (t < st){ r0[t] += r0[t+st]; r1[t] += r1[t+st]; }
            __syncthreads();
        }
        if (t < CQ){
            part[((long)blockIdx.x * C + t*4 + j)*2]     = r0[t];
            part[((long)blockIdx.x * C + t*4 + j)*2 + 1] = r1[t];
        }
        __syncthreads();
    }
}

__global__ __launch_bounds__(256)
void bn_stats_final2(const float* __restrict__ part, const float* __restrict__ g,
                     const float* __restrict__ bb, int C, int NB2, float* __restrict__ ss)
{
    const int c = blockIdx.x, t = threadIdx.x;
    float s = 0.f, s2 = 0.f;
    for (int i = t; i < NB2; i += 256){
        s  += part[((long)i*C + c)*2];
        s2 += part[((long)i*C + c)*2 + 1];
    }
    __shared__ float r0[256], r1[256];
    r0[t] = s; r1[t] = s2;
    __syncthreads();
    for (int st = 128; st > 0; st >>= 1){
        if (t < st){ r0[t] += r0[t+st]; r1[t] += r1[t+st]; }
        __syncthreads();
    }
    if (t == 0){
        const float invN = 1.f/524288.f;
        float m = r0[0]*invN;
        float v = r1[0]*invN - m*m;
        float sc = g[c]/sqrtf(v + 1e-5f);
        ss[c] = sc; ss[C+c] = bb[c] - m*sc;
    }
}

// apply BN+lrelu in place on NHWC bf16 (f1,f2,f3)
template<int C>
__global__ __launch_bounds__(256)
void bn_apply(u16* __restrict__ f, const float* __restrict__ ss, long n8)
{
    long i = (long)blockIdx.x*256 + threadIdx.x;
    if (i >= n8) return;
    u16x8 v = *(u16x8*)(f + i*8);
    int c0 = (int)((i*8) & (C-1));
#pragma unroll
    for (int j = 0; j < 8; j++){
        float xx = bf2f(v[j]);
        xx = lrelu(ss[c0+j]*xx + ss[C+c0+j]);
        v[j] = f2bf(xx);
    }
    *(u16x8*)(f + i*8) = v;
}

// ---------------------------------------------------------------------------
// f4 raw NHWC bf16 -> NCHW fp32 feat with BN+lrelu (LDS-tiled transpose).
// Block = 64-px strip of one image row: reads 64px x 256ch contiguous;
// WRITE PHASE COALESCED: 16 consecutive lanes write 16 consecutive float4s
// (256B contiguous) of ONE channel (round-9 bug: lane-per-channel writes
// scattered 16B x 64 at 1MB stride -> 12% HBM).  LDS pitch 258 u16 -> read
// stride 516 dwords = 4 banks apart -> ~2-way (free, m136).
// ---------------------------------------------------------------------------
__global__ __launch_bounds__(256)
void bn_expand_t(const u16* __restrict__ rawlo, const u16* __restrict__ rawhi,
                 const float* __restrict__ ss, float* __restrict__ feat, int b0)
{
    __shared__ u16 lds[64*258];
    const int bid = blockIdx.x;
    const int b = b0 + (bid >> 10);
    const int px0 = (bid & 1023) * 64;
    const long p0 = (((long)(b<<16) + px0)) << 8;
    const u16* src = (b < 6) ? (rawlo + p0) : (rawhi + (p0 - RAW_SPLIT));
    const int t = threadIdx.x;
#pragma unroll
    for (int it = 0; it < 8; ++it){
        int i = it*256 + t;
        int px = i >> 5, u = i & 31;
        *(u16x8*)&lds[px*258 + u*8] = *(const u16x8*)(src + (long)i*8);
    }
    __syncthreads();
#pragma unroll
    for (int it = 0; it < 16; ++it){
        int idx = it*256 + t;
        int ch = idx >> 4;            // 0..255
        int q  = idx & 15;            // 0..15 (float4 index within 64 px)
        const float sc = ss[ch], sh = ss[256 + ch];
        float4 o;
        o.x = lrelu(sc*bf2f(lds[(q*4+0)*258 + ch]) + sh);
        o.y = lrelu(sc*bf2f(lds[(q*4+1)*258 + ch]) + sh);
        o.z = lrelu(sc*bf2f(lds[(q*4+2)*258 + ch]) + sh);
        o.w = lrelu(sc*bf2f(lds[(q*4+3)*258 + ch]) + sh);
        *(float4*)(feat + (((long)(b*256 + ch)) << 16) + px0 + q*4) = o;
    }
}

// ---------------------------------------------------------------------------
// gather W from raw NHWC bf16 + inline BN (same arithmetic as bn_expand_t,
// so results match feat exactly).  One contiguous 512B read per site.
// ---------------------------------------------------------------------------
__global__ __launch_bounds__(256)
void gather_w_raw(const u16* __restrict__ rawlo, const u16* __restrict__ rawhi,
                  const float* __restrict__ ss, const int* __restrict__ hw,
                  float* __restrict__ outW)
{
    const int site = blockIdx.x;
    const int b = site >> 10;
    const int y = hw[site*2], x = hw[site*2 + 1];
    const int c = threadIdx.x;
    const long p = ((long)((b<<16) + (y<<8) + x)) << 8;
    const u16* base = (b < 6) ? (rawlo + p) : (rawhi + (p - RAW_SPLIT));
    float v = bf2f(base[c]);
    outW[(long)site*256 + c] = lrelu(ss[c]*v + ss[256 + c]);
}

__global__ __launch_bounds__(256)
void gather_patch(const float* __restrict__ x, const int* __restrict__ hw,
                  float* __restrict__ out)
{
    const long i = (long)blockIdx.x*256 + threadIdx.x;
    if (i >= 1204224L) return;
    const int px = (int)(i % 7);
    long r = i / 7;
    const int py = (int)(r % 7); r /= 7;
    const int c  = (int)(r % 3); r /= 3;
    const int s  = (int)(r % 1024);
    const int b  = (int)(r / 1024);
    const int site = b*1024 + s;
    const int yy = hw[site*2]     - 3 + py;
    const int xx = hw[site*2 + 1] - 3 + px;
    out[i] = x[(((long)(b*3 + c)) << 16) + ((long)yy << 8) + xx];
}

// ---------------------------------------------------------------------------
// decoder MLP, 8 sites per block (8x weight reuse per load)
// ---------------------------------------------------------------------------
__global__ __launch_bounds__(256)
void mlp8(const float* __restrict__ Wa, const float* __restrict__ l1w,
          const float* __restrict__ l1b, const float* __restrict__ l2w,
          const float* __restrict__ l2b, float* __restrict__ out)
{
    __shared__ float wa[2048];
    __shared__ float h[8][152];
    const int blk = blockIdx.x;
    const int t = threadIdx.x;
#pragma unroll
    for (int it = 0; it < 8; ++it)
        wa[it*256 + t] = Wa[(long)blk*2048 + it*256 + t];
    __syncthreads();
    if (t < PD){
        float a[8] = {0,0,0,0,0,0,0,0};
        const float* wr = l1w + t*256;
#pragma unroll 4
        for (int l = 0; l < 256; ++l){
            float wv = wr[l];
#pragma unroll
            for (int g = 0; g < 8; ++g) a[g] += wa[g*256 + l]*wv;
        }
        float bb = l1b[t];
#pragma unroll
        for (int g = 0; g < 8; ++g) h[g][t] = lrelu(a[g] + bb);
    }
    __syncthreads();
    if (t < PD){
        float r[8] = {0,0,0,0,0,0,0,0};
        const float* wr = l2w + t*PD;
        for (int p = 0; p < PD; ++p){
            float wv = wr[p];
#pragma unroll
            for (int g = 0; g < 8; ++g) r[g] += h[g][p]*wv;
        }
        float bb = l2b[t];
#pragma unroll
        for (int g = 0; g < 8; ++g)
            out[((long)(blk*8 + g))*PD + t] = r[g] + bb;
    }
}

extern "C" void kernel_launch(void* const* d_in, const int* in_sizes, int n_in,
                              void* d_out, int out_size, void* d_ws, size_t ws_size,
                              hipStream_t stream)
{
    const float* x   = (const float*)d_in[0];
    const int*   anc = (const int*)  d_in[1];
    const int*   pos = (const int*)  d_in[2];
    const float* w1  = (const float*)d_in[3];
    const float* g1  = (const float*)d_in[4];
    const float* b1  = (const float*)d_in[5];
    const float* w2  = (const float*)d_in[6];
    const float* g2  = (const float*)d_in[7];
    const float* b2  = (const float*)d_in[8];
    const float* w3  = (const float*)d_in[9];
    const float* g3  = (const float*)d_in[10];
    const float* b3  = (const float*)d_in[11];
    const float* w4  = (const float*)d_in[12];
    const float* g4  = (const float*)d_in[13];
    const float* b4  = (const float*)d_in[14];
    const float* l1w = (const float*)d_in[15];
    const float* l1b = (const float*)d_in[16];
    const float* l2w = (const float*)d_in[17];
    const float* l2b = (const float*)d_in[18];

    float* feat = (float*)d_out;
    float* oPR  = feat + OFF_PREAL;
    float* oRC  = feat + OFF_PRECON;
    float* oWA  = feat + OFF_WA;
    float* oWP  = feat + OFF_WP;

    // ws: f2 [0,64MB), f3 [64MB,192MB), f1 [128MB,160MB) (inside f3, dead before conv3)
    char* wsb = (char*)d_ws;
    u16* f2b = (u16*)wsb;
    u16* f3b = (u16*)(wsb + 67108864L);
    u16* f1b = (u16*)(wsb + 134217728L);

    // raw f4 bf16 NHWC: batches 0..5 in top of feat region; 6,7 in f2 region
    u16* rawlo = (u16*)d_out + 167772160L;    // byte offset 335544320
    u16* rawhi = f2b;                          // f2 dead after conv3

    // scratch inside d_out regions only written by later kernels
    u16* Wt2 = (u16*)oWA;                      // dead after conv2
    u16* Wt3 = Wt2 + 18432;                    // dead after conv3
    u16* Wt4 = Wt3 + 73728;                    // dead after conv4
    float* part = oWP;                         // dead after stats_final; gather_w(pos) overwrites
    float* ss1 = oRC, *ss2 = oRC + 64, *ss3 = oRC + 192, *ss4 = oRC + 448;  // dead before mlp8

    prep_w<<<72,   256, 0, stream>>>(w2, Wt2, 64, 32);
    prep_w<<<288,  256, 0, stream>>>(w3, Wt3, 128, 64);
    prep_w<<<1152, 256, 0, stream>>>(w4, Wt4, 256, 128);

    conv1_direct<<<dim3(256,8), 256, 0, stream>>>(x, w1, f1b);
    bn_stats_nhwc<32><<<1024, 256, 0, stream>>>(f1b, part);
    bn_stats_final2<<<32, 256, 0, stream>>>(part, g1, b1, 32, 1024, ss1);
    bn_apply<32><<<8192, 256, 0, stream>>>(f1b, ss1, 2097152L);

    conv_mfma<32,64,false><<<dim3(256,8), 512, 0, stream>>>(f1b, Wt2, f2b, nullptr, part);
    bn_stats_final2<<<64, 256, 0, stream>>>(part, g2, b2, 64, 4096, ss2);
    bn_apply<64><<<16384, 256, 0, stream>>>(f2b, ss2, 4194304L);

    conv_mfma<64,128,false><<<dim3(256,8), 512, 0, stream>>>(f2b, Wt3, f3b, nullptr, part);
    bn_stats_final2<<<128, 256, 0, stream>>>(part, g3, b3, 128, 4096, ss3);
    bn_apply<128><<<32768, 256, 0, stream>>>(f3b, ss3, 8388608L);

    conv_mfma<128,256,true><<<dim3(256,8), 512, 0, stream>>>(f3b, Wt4, rawlo, rawhi, part);
    bn_stats_final2<<<256, 256, 0, stream>>>(part, g4, b4, 256, 4096, ss4);

    // gathers read RAW f4 (+inline BN, identical arithmetic to expand) BEFORE
    // the expand kernels clobber the raw regions.
    gather_w_raw<<<8192, 256, 0, stream>>>(rawlo, rawhi, ss4, anc, oWA);
    gather_w_raw<<<8192, 256, 0, stream>>>(rawlo, rawhi, ss4, pos, oWP);
    gather_patch<<<4704, 256, 0, stream>>>(x, anc, oPR);

    // expand raw -> fp32 feat (transpose).  Safety by launch order:
    //  E1: b 0..4  writes feat bytes [0, 335.5MB)       (below rawlo)
    //  E2: b 5     writes [335.5, 402.7) = raw of b0,b1 (read by E1)
    //  E3: b 6,7   reads ws, writes [402.7, 537) = raw of b2..b5 (read E1/E2)
    bn_expand_t<<<5120, 256, 0, stream>>>(rawlo, rawhi, ss4, feat, 0);
    bn_expand_t<<<1024, 256, 0, stream>>>(rawlo, rawhi, ss4, feat, 5);
    bn_expand_t<<<2048, 256, 0, stream>>>(rawlo, rawhi, ss4, feat, 6);

    // mlp last: it overwrites oRC (incl. ss slots) after all consumers done
    mlp8<<<1024, 256, 0, stream>>>(oWA, l1w, l1b, l2w, l2b, oRC);
}

// Round 11
// 803.274 us; speedup vs baseline: 1.6435x; 1.0258x over previous
//
#include <hip/hip_runtime.h>
#include <hip/hip_bf16.h>

typedef unsigned short u16;
typedef short bf16x8 __attribute__((ext_vector_type(8)));
typedef float f32x4 __attribute__((ext_vector_type(4)));
typedef unsigned short u16x8 __attribute__((ext_vector_type(8)));

#define PD 147

static const long OFF_PREAL = 134217728L;
static const long OFF_PRECON= 135421952L;
static const long OFF_WA    = 136626176L;
static const long OFF_WP    = 138723328L;

// raw f4 bf16 NHWC split: elems [0,100663296) (= batches 0..5) at d_out
// u16-offset 167772160 (top 201.3MB of feat region); batches 6,7 in ws f2
// region (exactly 64 MiB).
static const long RAW_SPLIT = 100663296L;

__device__ __forceinline__ float lrelu(float v){ return v >= 0.f ? v : 0.01f*v; }

__device__ __forceinline__ float bf2f(u16 u){
    union { unsigned int i; float f; } x; x.i = ((unsigned int)u) << 16; return x.f;
}
__device__ __forceinline__ u16 f2bf(float f){
    __hip_bfloat16 h = __float2bfloat16(f);
    return *reinterpret_cast<u16*>(&h);
}

__device__ __forceinline__ void gload16(const void* g, void* l){
    __builtin_amdgcn_global_load_lds((const __attribute__((address_space(1))) void*)g,
                                     (__attribute__((address_space(3))) void*)l, 16, 0, 0);
}

// ---------------------------------------------------------------------------
// MFMA implicit-GEMM 3x3 SAME conv.  16x16 spatial tile x all K_OUT channels
// per block.  8 waves (2M x 4N).  Input NHWC bf16 **RAW** (pre-BN); BN+lrelu
// of the previous layer is fused into A-staging (reg-stage: load->reg,
// lrelu(sc*x+sh), ds_write_b128).  Arithmetic identical to the old separate
// bn_apply pass (same raw bf16 in, same f32 ops, same bf16 rounding).
// Weights pre-transposed [tap][k_out][c_in] bf16, staged via global_load_lds
// (wave-uniform dst — m104/m108).  BK=96 steps (one dy-row = 3 taps).
// Halo zeros written explicitly each restage (activated-domain zero pad).
// Fused deterministic BN partial stats of THIS layer's raw output.
// Output: NHWC bf16 raw.  SPLIT: batches 0..5 -> out_, 6,7 -> rawhi.
// ---------------------------------------------------------------------------
template<int CIN, int KOUT, bool SPLIT>
__global__ __launch_bounds__(512)
void conv_mfma(const u16* __restrict__ fin, const u16* __restrict__ wt,
               const float* __restrict__ ssin,
               void* __restrict__ out_, u16* __restrict__ rawhi,
               float* __restrict__ part)
{
    constexpr int CC = CIN / 32;
    constexpr int NS3 = CC * 3;                        // dy-row steps
    constexpr int NF = KOUT / 64;
    constexpr int ABYTES = 2 * 324 * 32 * 2;           // dbuf 18x18x32 bf16
    constexpr int BQ = 3 * KOUT * 4;                   // quarters per B buffer
    constexpr int NB3 = (BQ + 511) / 512;              // stage_b rounds
    constexpr int BBYTES = 2 * BQ * 16;
    constexpr int EPIB = 256 * KOUT * 2;
    constexpr int SB = (ABYTES + BBYTES) > EPIB ? (ABYTES + BBYTES) : EPIB;
    __shared__ __align__(16) char smem[SB];
    u16* As = (u16*)smem;
    u16* Bs = (u16*)(smem + ABYTES);

    const int tid = threadIdx.x;
    const int w = tid >> 6, lane = tid & 63;
    const int wm = w >> 2, wn = w & 3;
    const int tile = blockIdx.x;
    const int tx0 = (tile & 15) << 4, ty0 = (tile >> 4) << 4;
    const int b = blockIdx.y;
    const long pixbase = (long)b << 16;
    const int hi = lane >> 4;
    const int quarter = lane & 3;                      // q&3 == lane&3 for all rounds

    f32x4 acc[8][NF];
#pragma unroll
    for (int m = 0; m < 8; m++)
#pragma unroll
        for (int n = 0; n < NF; n++) acc[m][n] = (f32x4){0.f,0.f,0.f,0.f};

    // per-lane BN params for the A-channels this lane stages (8 channels)
    float sc8[8], sh8[8];
    auto load_ss = [&](int cc){
        int c0 = cc*32 + quarter*8;
#pragma unroll
        for (int j = 0; j < 8; j++){
            sc8[j] = ssin[c0 + j];
            sh8[j] = ssin[CIN + c0 + j];
        }
    };

    // A reg-staging: global raw bf16 -> BN+lrelu -> bf16 -> per-lane ds_write
    auto stage_a_round = [&](int cc, int buf, int r){
        int q = r*512 + w*64 + lane;
        int pf = q >> 2;
        int ly = pf / 18, lx = pf - ly*18;
        int gy = ty0 + ly - 1, gx = tx0 + lx - 1;
        bool ok = (q < 1296) && ((unsigned)gy < 256u) && ((unsigned)gx < 256u);
        u16x8 o = (u16x8){0,0,0,0,0,0,0,0};
        if (ok){
            u16x8 v = *(const u16x8*)(fin + ((pixbase + (gy<<8) + gx) * CIN + cc*32 + quarter*8));
#pragma unroll
            for (int j = 0; j < 8; j++)
                o[j] = f2bf(lrelu(sc8[j]*bf2f(v[j]) + sh8[j]));
        }
        if (q < 1296)
            *(u16x8*)(As + buf*(324*32) + q*8) = o;    // per-lane ds_write (halo = 0)
    };
    auto stage_b3 = [&](int s, int buf){
        int cc = s / 3, dyr = s - cc*3;
        int t0 = dyr * 3;
        u16* dstbase = Bs + buf * (BQ*16/2);
#pragma unroll
        for (int r = 0; r < NB3; ++r){
            int q = r*512 + w*64 + lane;
            int tl = q / (KOUT*4);
            int qq = q - tl*(KOUT*4);
            int k = qq >> 2, bq = qq & 3;
            const u16* src = wt + (((long)(t0+tl)*KOUT + k) * CIN + cc*32 + bq*8);
            u16* dst = dstbase + (r*512 + w*64) * 8;   // WAVE-UNIFORM base (m104)
            if (q < BQ) gload16(src, dst);             // mask is wave-uniform
        }
    };

    // prologue
    load_ss(0);
    stage_a_round(0, 0, 0); stage_a_round(0, 0, 1); stage_a_round(0, 0, 2);
    stage_b3(0, 0);
    __syncthreads();

#pragma unroll 1
    for (int s = 0; s < NS3; ++s){
        int cc = s / 3, dyr = s - cc*3;
        if (s + 1 < NS3) stage_b3(s + 1, (s + 1) & 1);
        if (cc + 1 < CC){
            if (dyr == 0) load_ss(cc + 1);
            stage_a_round(cc + 1, (cc + 1) & 1, dyr);
        }

        const u16* Ab = As + (cc & 1) * (324*32);
        const u16* Bb = Bs + (s & 1) * (BQ*16/2);
#pragma unroll
        for (int t = 0; t < 3; ++t){
            bf16x8 av[8];
#pragma unroll
            for (int m = 0; m < 8; m++){
                int pf = (wm*8 + m + dyr)*18 + (lane & 15) + t;
                av[m] = *(const bf16x8*)(Ab + pf*32 + hi*8);
            }
            bf16x8 bv[NF];
#pragma unroll
            for (int n = 0; n < NF; n++){
                int ch = (wn*NF + n)*16 + (lane & 15);
                bv[n] = *(const bf16x8*)(Bb + (t*KOUT + ch)*32 + hi*8);
            }
#pragma unroll
            for (int m = 0; m < 8; m++)
#pragma unroll
                for (int n = 0; n < NF; n++)
                    acc[m][n] = __builtin_amdgcn_mfma_f32_16x16x32_bf16(av[m], bv[n], acc[m][n], 0, 0, 0);
        }
        __syncthreads();   // drains vmcnt+lgkmcnt (next bufs ready) + readers done
    }

    // ---- fused BN partial stats (fp32, pre-rounding), deterministic slots ----
    {
        const int bid = blockIdx.y * 256 + blockIdx.x;
        const long slot = (long)bid * 2 + wm;
#pragma unroll
        for (int n = 0; n < NF; n++){
            float s = 0.f, s2 = 0.f;
#pragma unroll
            for (int m = 0; m < 8; m++)
#pragma unroll
                for (int j = 0; j < 4; j++){
                    float v = acc[m][n][j];
                    s += v; s2 += v*v;
                }
            s += __shfl_down(s, 32); s2 += __shfl_down(s2, 32);
            s += __shfl_down(s, 16); s2 += __shfl_down(s2, 16);
            if (lane < 16){
                int ch = (wn*NF + n)*16 + lane;
                long off = (slot*KOUT + ch)*2;
                part[off]   = s;
                part[off+1] = s2;
            }
        }
    }

    // block-wide LDS transpose -> NHWC bf16 raw, fully coalesced stores
    {
        u16* ep = (u16*)smem;
        u16* outh = (u16*)out_;
        if (SPLIT && b >= 6) outh = rawhi - RAW_SPLIT;
#pragma unroll
        for (int m = 0; m < 8; m++)
#pragma unroll
            for (int n = 0; n < NF; n++){
                int ch = (wn*NF + n)*16 + (lane&15);
#pragma unroll
                for (int j = 0; j < 4; j++){
                    int px = wm*128 + m*16 + (lane>>4)*4 + j;
                    ep[px*KOUT + ch] = f2bf(acc[m][n][j]);
                }
            }
        __syncthreads();
        const int n16 = 256*KOUT/8;
        const int upr = KOUT*2;                 // 16B units per spatial row
        for (int i = tid; i < n16; i += 512){
            int py = i / upr;
            int rem = i - py*upr;
            long ga = (pixbase + ((ty0+py)<<8) + tx0) * KOUT + (long)rem*8;
            *(int4*)(outh + ga) = *(int4*)(ep + (long)i*8);
        }
    }
}

// ---------------------------------------------------------------------------
// conv1: 3->32 direct (tiny), output NHWC bf16 raw
// ---------------------------------------------------------------------------
__global__ __launch_bounds__(256)
void conv1_direct(const float* __restrict__ x, const float* __restrict__ w1, u16* __restrict__ f1)
{
    __shared__ float wl[864];
    const int t = threadIdx.x;
    for (int i = t; i < 864; i += 256) wl[i] = w1[i];
    __syncthreads();
    const int y = blockIdx.x, b = blockIdx.y;
    float acc[32];
#pragma unroll
    for (int k = 0; k < 32; k++) acc[k] = 0.f;
    const long ib = (long)b*3*65536;
    for (int c = 0; c < 3; c++){
#pragma unroll
        for (int dy = 0; dy < 3; dy++){
            int gy = y + dy - 1;
#pragma unroll
            for (int dx = 0; dx < 3; dx++){
                int gx = t + dx - 1;
                float v = 0.f;
                if ((unsigned)gy < 256u && (unsigned)gx < 256u)
                    v = x[ib + c*65536 + (gy<<8) + gx];
                const float* wp = &wl[c*9 + dy*3 + dx];
#pragma unroll
                for (int k = 0; k < 32; k++) acc[k] += v * wp[k*27];
            }
        }
    }
    u16 ub[32];
#pragma unroll
    for (int k = 0; k < 32; k++) ub[k] = f2bf(acc[k]);
    u16* dst = f1 + ((long)(b*65536 + (y<<8) + t)) * 32;
#pragma unroll
    for (int j = 0; j < 4; j++) *(int4*)(dst + j*8) = *(int4*)(ub + j*8);
}

// weight transpose: wt[tap][k][c] = bf16(w[k][c][tap])
__global__ __launch_bounds__(256)
void prep_w(const float* __restrict__ w, u16* __restrict__ wt, int K, int C)
{
    int i = blockIdx.x*256 + threadIdx.x;
    if (i >= 9*K*C) return;
    int c = i % C; int r = i / C; int k = r % K; int tap = r / K;
    wt[i] = f2bf(w[((long)k*C + c)*9 + tap]);
}

// ---------------------------------------------------------------------------
// BN stats over NHWC bf16 (layer 1 only)
// ---------------------------------------------------------------------------
template<int C>
__global__ __launch_bounds__(256)
void bn_stats_nhwc(const u16* __restrict__ f, float* __restrict__ part)
{
    constexpr int CQ = C/4;
    constexpr int SUBS = 256/CQ;
    const int t = threadIdx.x;
    const int cq = t & (CQ-1);
    const int sub = t / CQ;
    const long rowbase = (long)blockIdx.x * 512;
    float s[4] = {0,0,0,0}, q2[4] = {0,0,0,0};
    for (int r = sub; r < 512; r += SUBS){
        ushort4 v = *(const ushort4*)(f + (rowbase + r)*C + cq*4);
        float x0 = bf2f(v.x), x1 = bf2f(v.y), x2 = bf2f(v.z), x3 = bf2f(v.w);
        s[0]+=x0; q2[0]+=x0*x0; s[1]+=x1; q2[1]+=x1*x1;
        s[2]+=x2; q2[2]+=x2*x2; s[3]+=x3; q2[3]+=x3*x3;
    }
    __shared__ float r0[256], r1[256];
    for (int j = 0; j < 4; j++){
        r0[t] = s[j]; r1[t] = q2[j];
        __syncthreads();
        for (int st = 128; st >= CQ; st >>= 1){
            if (t < st){ r0[t] += r0[t+st]; r1[t] += r1[t+st]; }
            __syncthreads();
        }
        if (t < CQ){
            part[((long)blockIdx.x * C + t*4 + j)*2]     = r0[t];
            part[((long)blockIdx.x * C + t*4 + j)*2 + 1] = r1[t];
        }
        __syncthreads();
    }
}

__global__ __launch_bounds__(256)
void bn_stats_final2(const float* __restrict__ part, const float* __restrict__ g,
                     const float* __restrict__ bb, int C, int NB2, float* __restrict__ ss)
{
    const int c = blockIdx.x, t = threadIdx.x;
    float s = 0.f, s2 = 0.f;
    for (int i = t; i < NB2; i += 256){
        s  += part[((long)i*C + c)*2];
        s2 += part[((long)i*C + c)*2 + 1];
    }
    __shared__ float r0[256], r1[256];
    r0[t] = s; r1[t] = s2;
    __syncthreads();
    for (int st = 128; st > 0; st >>= 1){
        if (t < st){ r0[t] += r0[t+st]; r1[t] += r1[t+st]; }
        __syncthreads();
    }
    if (t == 0){
        const float invN = 1.f/524288.f;
        float m = r0[0]*invN;
        float v = r1[0]*invN - m*m;
        float sc = g[c]/sqrtf(v + 1e-5f);
        ss[c] = sc; ss[C+c] = bb[c] - m*sc;
    }
}

// ---------------------------------------------------------------------------
// f4 raw NHWC bf16 -> NCHW fp32 feat with BN+lrelu (LDS-tiled transpose).
// 64-px strip per block; writes: 16 consecutive lanes write 16 consecutive
// float4s (256B contiguous) of one channel.
// ---------------------------------------------------------------------------
__global__ __launch_bounds__(256)
void bn_expand_t(const u16* __restrict__ rawlo, const u16* __restrict__ rawhi,
                 const float* __restrict__ ss, float* __restrict__ feat, int b0)
{
    __shared__ u16 lds[64*258];
    const int bid = blockIdx.x;
    const int b = b0 + (bid >> 10);
    const int px0 = (bid & 1023) * 64;
    const long p0 = (((long)(b<<16) + px0)) << 8;
    const u16* src = (b < 6) ? (rawlo + p0) : (rawhi + (p0 - RAW_SPLIT));
    const int t = threadIdx.x;
#pragma unroll
    for (int it = 0; it < 8; ++it){
        int i = it*256 + t;
        int px = i >> 5, u = i & 31;
        *(u16x8*)&lds[px*258 + u*8] = *(const u16x8*)(src + (long)i*8);
    }
    __syncthreads();
#pragma unroll
    for (int it = 0; it < 16; ++it){
        int idx = it*256 + t;
        int ch = idx >> 4;
        int q  = idx & 15;
        const float sc = ss[ch], sh = ss[256 + ch];
        float4 o;
        o.x = lrelu(sc*bf2f(lds[(q*4+0)*258 + ch]) + sh);
        o.y = lrelu(sc*bf2f(lds[(q*4+1)*258 + ch]) + sh);
        o.z = lrelu(sc*bf2f(lds[(q*4+2)*258 + ch]) + sh);
        o.w = lrelu(sc*bf2f(lds[(q*4+3)*258 + ch]) + sh);
        *(float4*)(feat + (((long)(b*256 + ch)) << 16) + px0 + q*4) = o;
    }
}

// ---------------------------------------------------------------------------
// gather W from raw NHWC bf16 + inline BN (matches bn_expand_t arithmetic)
// ---------------------------------------------------------------------------
__global__ __launch_bounds__(256)
void gather_w_raw(const u16* __restrict__ rawlo, const u16* __restrict__ rawhi,
                  const float* __restrict__ ss, const int* __restrict__ hw,
                  float* __restrict__ outW)
{
    const int site = blockIdx.x;
    const int b = site >> 10;
    const int y = hw[site*2], x = hw[site*2 + 1];
    const int c = threadIdx.x;
    const long p = ((long)((b<<16) + (y<<8) + x)) << 8;
    const u16* base = (b < 6) ? (rawlo + p) : (rawhi + (p - RAW_SPLIT));
    float v = bf2f(base[c]);
    outW[(long)site*256 + c] = lrelu(ss[c]*v + ss[256 + c]);
}

__global__ __launch_bounds__(256)
void gather_patch(const float* __restrict__ x, const int* __restrict__ hw,
                  float* __restrict__ out)
{
    const long i = (long)blockIdx.x*256 + threadIdx.x;
    if (i >= 1204224L) return;
    const int px = (int)(i % 7);
    long r = i / 7;
    const int py = (int)(r % 7); r /= 7;
    const int c  = (int)(r % 3); r /= 3;
    const int s  = (int)(r % 1024);
    const int b  = (int)(r / 1024);
    const int site = b*1024 + s;
    const int yy = hw[site*2]     - 3 + py;
    const int xx = hw[site*2 + 1] - 3 + px;
    out[i] = x[(((long)(b*3 + c)) << 16) + ((long)yy << 8) + xx];
}

// ---------------------------------------------------------------------------
// decoder MLP, 8 sites per block (8x weight reuse per load)
// ---------------------------------------------------------------------------
__global__ __launch_bounds__(256)
void mlp8(const float* __restrict__ Wa, const float* __restrict__ l1w,
          const float* __restrict__ l1b, const float* __restrict__ l2w,
          const float* __restrict__ l2b, float* __restrict__ out)
{
    __shared__ float wa[2048];
    __shared__ float h[8][152];
    const int blk = blockIdx.x;
    const int t = threadIdx.x;
#pragma unroll
    for (int it = 0; it < 8; ++it)
        wa[it*256 + t] = Wa[(long)blk*2048 + it*256 + t];
    __syncthreads();
    if (t < PD){
        float a[8] = {0,0,0,0,0,0,0,0};
        const float* wr = l1w + t*256;
#pragma unroll 4
        for (int l = 0; l < 256; ++l){
            float wv = wr[l];
#pragma unroll
            for (int g = 0; g < 8; ++g) a[g] += wa[g*256 + l]*wv;
        }
        float bb = l1b[t];
#pragma unroll
        for (int g = 0; g < 8; ++g) h[g][t] = lrelu(a[g] + bb);
    }
    __syncthreads();
    if (t < PD){
        float r[8] = {0,0,0,0,0,0,0,0};
        const float* wr = l2w + t*PD;
        for (int p = 0; p < PD; ++p){
            float wv = wr[p];
#pragma unroll
            for (int g = 0; g < 8; ++g) r[g] += h[g][p]*wv;
        }
        float bb = l2b[t];
#pragma unroll
        for (int g = 0; g < 8; ++g)
            out[((long)(blk*8 + g))*PD + t] = r[g] + bb;
    }
}

extern "C" void kernel_launch(void* const* d_in, const int* in_sizes, int n_in,
                              void* d_out, int out_size, void* d_ws, size_t ws_size,
                              hipStream_t stream)
{
    const float* x   = (const float*)d_in[0];
    const int*   anc = (const int*)  d_in[1];
    const int*   pos = (const int*)  d_in[2];
    const float* w1  = (const float*)d_in[3];
    const float* g1  = (const float*)d_in[4];
    const float* b1  = (const float*)d_in[5];
    const float* w2  = (const float*)d_in[6];
    const float* g2  = (const float*)d_in[7];
    const float* b2  = (const float*)d_in[8];
    const float* w3  = (const float*)d_in[9];
    const float* g3  = (const float*)d_in[10];
    const float* b3  = (const float*)d_in[11];
    const float* w4  = (const float*)d_in[12];
    const float* g4  = (const float*)d_in[13];
    const float* b4  = (const float*)d_in[14];
    const float* l1w = (const float*)d_in[15];
    const float* l1b = (const float*)d_in[16];
    const float* l2w = (const float*)d_in[17];
    const float* l2b = (const float*)d_in[18];

    float* feat = (float*)d_out;
    float* oPR  = feat + OFF_PREAL;
    float* oRC  = feat + OFF_PRECON;
    float* oWA  = feat + OFF_WA;
    float* oWP  = feat + OFF_WP;

    // ws: f2 [0,64MB), f3 [64MB,192MB), f1 [128MB,160MB) (inside f3, dead before conv3)
    char* wsb = (char*)d_ws;
    u16* f2b = (u16*)wsb;
    u16* f3b = (u16*)(wsb + 67108864L);
    u16* f1b = (u16*)(wsb + 134217728L);

    // raw f4 bf16 NHWC: batches 0..5 in top of feat region; 6,7 in f2 region
    u16* rawlo = (u16*)d_out + 167772160L;    // byte offset 335544320
    u16* rawhi = f2b;                          // f2 dead after conv3

    // scratch inside d_out regions only written by later kernels
    u16* Wt2 = (u16*)oWA;                      // dead after conv2
    u16* Wt3 = Wt2 + 18432;                    // dead after conv3
    u16* Wt4 = Wt3 + 73728;                    // dead after conv4
    float* part = oWP;                         // dead after stats_final; gather_w(pos) overwrites
    float* ss1 = oRC, *ss2 = oRC + 64, *ss3 = oRC + 192, *ss4 = oRC + 448;  // dead before mlp8

    prep_w<<<72,   256, 0, stream>>>(w2, Wt2, 64, 32);
    prep_w<<<288,  256, 0, stream>>>(w3, Wt3, 128, 64);
    prep_w<<<1152, 256, 0, stream>>>(w4, Wt4, 256, 128);

    // conv1 -> raw f1; stats on raw f1 -> ss1 (no apply pass: conv2 folds BN)
    conv1_direct<<<dim3(256,8), 256, 0, stream>>>(x, w1, f1b);
    bn_stats_nhwc<32><<<1024, 256, 0, stream>>>(f1b, part);
    bn_stats_final2<<<32, 256, 0, stream>>>(part, g1, b1, 32, 1024, ss1);

    conv_mfma<32,64,false><<<dim3(256,8), 512, 0, stream>>>(f1b, Wt2, ss1, f2b, nullptr, part);
    bn_stats_final2<<<64, 256, 0, stream>>>(part, g2, b2, 64, 4096, ss2);

    conv_mfma<64,128,false><<<dim3(256,8), 512, 0, stream>>>(f2b, Wt3, ss2, f3b, nullptr, part);
    bn_stats_final2<<<128, 256, 0, stream>>>(part, g3, b3, 128, 4096, ss3);

    conv_mfma<128,256,true><<<dim3(256,8), 512, 0, stream>>>(f3b, Wt4, ss3, rawlo, rawhi, part);
    bn_stats_final2<<<256, 256, 0, stream>>>(part, g4, b4, 256, 4096, ss4);

    // gathers read RAW f4 (+inline BN) BEFORE the expand kernels clobber raw
    gather_w_raw<<<8192, 256, 0, stream>>>(rawlo, rawhi, ss4, anc, oWA);
    gather_w_raw<<<8192, 256, 0, stream>>>(rawlo, rawhi, ss4, pos, oWP);
    gather_patch<<<4704, 256, 0, stream>>>(x, anc, oPR);

    // expand raw -> fp32 feat (transpose).  Safety by launch order:
    //  E1: b 0..4  writes feat bytes [0, 335.5MB)       (below rawlo)
    //  E2: b 5     writes [335.5, 402.7) = raw of b0,b1 (read by E1)
    //  E3: b 6,7   reads ws, writes [402.7, 537) = raw of b2..b5 (read E1/E2)
    bn_expand_t<<<5120, 256, 0, stream>>>(rawlo, rawhi, ss4, feat, 0);
    bn_expand_t<<<1024, 256, 0, stream>>>(rawlo, rawhi, ss4, feat, 5);
    bn_expand_t<<<2048, 256, 0, stream>>>(rawlo, rawhi, ss4, feat, 6);

    // mlp last: it overwrites oRC (incl. ss slots) after all consumers done
    mlp8<<<1024, 256, 0, stream>>>(oWA, l1w, l1b, l2w, l2b, oRC);
}

// Round 12
// 766.487 us; speedup vs baseline: 1.7224x; 1.0480x over previous
//
#include <hip/hip_runtime.h>
#include <hip/hip_bf16.h>

typedef unsigned short u16;
typedef short bf16x8 __attribute__((ext_vector_type(8)));
typedef float f32x4 __attribute__((ext_vector_type(4)));
typedef unsigned short u16x8 __attribute__((ext_vector_type(8)));

#define PD 147

static const long OFF_PREAL = 134217728L;
static const long OFF_PRECON= 135421952L;
static const long OFF_WA    = 136626176L;
static const long OFF_WP    = 138723328L;

// raw f4 bf16 NHWC split: elems [0,100663296) (= batches 0..5) at d_out
// u16-offset 167772160 (top 201.3MB of feat region); batches 6,7 in ws f2.
static const long RAW_SPLIT = 100663296L;

__device__ __forceinline__ float lrelu(float v){ return v >= 0.f ? v : 0.01f*v; }

__device__ __forceinline__ float bf2f(u16 u){
    union { unsigned int i; float f; } x; x.i = ((unsigned int)u) << 16; return x.f;
}
__device__ __forceinline__ u16 f2bf(float f){
    __hip_bfloat16 h = __float2bfloat16(f);
    return *reinterpret_cast<u16*>(&h);
}

__device__ __forceinline__ void gload16(const void* g, void* l){
    __builtin_amdgcn_global_load_lds((const __attribute__((address_space(1))) void*)g,
                                     (__attribute__((address_space(3))) void*)l, 16, 0, 0);
}

// ---------------------------------------------------------------------------
// MFMA implicit-GEMM 3x3 SAME conv — TLP-oriented geometry.
// 256-thread blocks (4 waves), wave tile = 64 px x 64 ch (acc = 64 VGPR),
// block = 16x16 px x 64 OUTPUT CHANNELS (KOUT split via blockIdx.y).
// __launch_bounds__(256,4) caps VGPR at 128 -> 3-4 blocks/CU co-resident:
// barrier/drain stalls of one block hidden by other blocks (m114 mechanism
// that the 1-block/CU 8-wave version could not exploit).
// LDS ~33KB: A single-buffered 18x18x32 (restaged per cc with extra barrier),
// B double-buffered 64ch x 32 per tap via global_load_lds (wave-uniform dst,
// m104).  A reg-staged with fused BN+lrelu of the previous layer (identical
// arithmetic to round-10's bn_apply).  Fused deterministic BN partial stats
// (4 wave partials -> LDS reduce -> one 64-ch slice of part per block).
// Output NHWC bf16 raw; SPLIT: batches 0..5 -> out_, 6,7 -> rawhi.
// Grid (x=tile, y=bz, z=b): the bz copies of a tile are 256 ids apart ->
// same XCD (id%8) -> A restage served by L2.
// ---------------------------------------------------------------------------
template<int CIN, int KOUT, bool SPLIT>
__global__ __launch_bounds__(256, 4)
void conv_mfma(const u16* __restrict__ fin, const u16* __restrict__ wt,
               const float* __restrict__ ssin,
               void* __restrict__ out_, u16* __restrict__ rawhi,
               float* __restrict__ part)
{
    constexpr int CC = CIN / 32;
    constexpr int NSTEPS = CC * 9;                 // one tap per step
    constexpr int ABYTES = 324 * 32 * 2;           // single-buffered A
    constexpr int BBYTES = 2 * 64 * 32 * 2;        // dbuf B: 64ch x 32 x bf16
    constexpr int EPIB = 256 * 64 * 2;             // epilogue transpose
    constexpr int SB = (ABYTES + BBYTES) > EPIB ? (ABYTES + BBYTES) : EPIB;
    __shared__ __align__(16) char smem[SB];
    u16* As = (u16*)smem;
    u16* Bs = (u16*)(smem + ABYTES);

    const int tid = threadIdx.x;
    const int w = tid >> 6, lane = tid & 63;
    const int tile = blockIdx.x;
    const int tx0 = (tile & 15) << 4, ty0 = (tile >> 4) << 4;
    const int bz = blockIdx.y;                     // output-channel quarter
    const int b  = blockIdx.z;
    const long pixbase = (long)b << 16;
    const int hi = lane >> 4;
    const int quarter = tid & 3;

    f32x4 acc[4][4];
#pragma unroll
    for (int m = 0; m < 4; m++)
#pragma unroll
        for (int n = 0; n < 4; n++) acc[m][n] = (f32x4){0.f,0.f,0.f,0.f};

    // A reg-staging: raw bf16 -> BN+lrelu -> bf16 -> per-lane ds_write.
    // Per-lane dst is legal here (plain ds_write, not global_load_lds).
    auto stage_a = [&](int cc){
        float sc8[8], sh8[8];
        int c0 = cc*32 + quarter*8;
#pragma unroll
        for (int j = 0; j < 8; j++){
            sc8[j] = ssin[c0 + j];
            sh8[j] = ssin[CIN + c0 + j];
        }
#pragma unroll
        for (int r = 0; r < 6; ++r){
            int q = r*256 + tid;
            if (q < 1296){
                int pf = q >> 2;
                int ly = pf / 18, lx = pf - ly*18;
                int gy = ty0 + ly - 1, gx = tx0 + lx - 1;
                u16x8 o = (u16x8){0,0,0,0,0,0,0,0};
                if ((unsigned)gy < 256u && (unsigned)gx < 256u){
                    u16x8 v = *(const u16x8*)(fin + ((pixbase + (gy<<8) + gx) * CIN + cc*32 + quarter*8));
#pragma unroll
                    for (int j = 0; j < 8; j++)
                        o[j] = f2bf(lrelu(sc8[j]*bf2f(v[j]) + sh8[j]));
                }
                *(u16x8*)(As + q*8) = o;           // halo stays zero
            }
        }
    };
    // B staging: one gload16 per thread (64ch x 4 quarters = 256 = blockDim)
    auto stage_b = [&](int s, int buf){
        int cc2 = s / 9, tap = s - cc2*9;
        const u16* src = wt + (((long)tap*KOUT + bz*64 + (tid>>2)) * CIN + cc2*32 + (tid&3)*8);
        u16* dst = Bs + buf*2048 + (w*64)*8;       // WAVE-UNIFORM base (m104)
        gload16(src, dst);
    };

    // prologue
    stage_a(0);
    stage_b(0, 0);
    __syncthreads();

#pragma unroll 1
    for (int s = 0; s < NSTEPS; ++s){
        int cc = s / 9, tap = s - cc*9;
        if (s + 1 < NSTEPS) stage_b(s + 1, (s + 1) & 1);

        int dy = tap / 3, dx = tap - dy*3;
        const u16* Bb = Bs + (s & 1) * 2048;
        bf16x8 av[4];
#pragma unroll
        for (int m = 0; m < 4; m++){
            int pf = (w*4 + m + dy)*18 + (lane & 15) + dx;
            av[m] = *(const bf16x8*)(As + pf*32 + hi*8);
        }
        bf16x8 bv[4];
#pragma unroll
        for (int n = 0; n < 4; n++){
            int chl = n*16 + (lane & 15);
            bv[n] = *(const bf16x8*)(Bb + chl*32 + hi*8);
        }
#pragma unroll
        for (int m = 0; m < 4; m++)
#pragma unroll
            for (int n = 0; n < 4; n++)
                acc[m][n] = __builtin_amdgcn_mfma_f32_16x16x32_bf16(av[m], bv[n], acc[m][n], 0, 0, 0);

        __syncthreads();   // drains vmcnt/lgkmcnt (next B ready) + readers done
        if (tap == 8 && cc + 1 < CC){
            stage_a(cc + 1);       // safe: all reads of A(cc) completed
            __syncthreads();       // A(cc+1) visible before next step
        }
    }

    // ---- fused BN partial stats: 4 wave partials -> LDS -> 64-ch slice ----
    {
        float* sred = (float*)smem;                // [2][4][64], aliases As
#pragma unroll
        for (int n = 0; n < 4; n++){
            float s = 0.f, s2 = 0.f;
#pragma unroll
            for (int m = 0; m < 4; m++)
#pragma unroll
                for (int j = 0; j < 4; j++){
                    float v = acc[m][n][j];
                    s += v; s2 += v*v;
                }
            s += __shfl_down(s, 32); s2 += __shfl_down(s2, 32);
            s += __shfl_down(s, 16); s2 += __shfl_down(s2, 16);
            if (lane < 16){
                int ch = n*16 + lane;
                sred[w*64 + ch]       = s;
                sred[256 + w*64 + ch] = s2;
            }
        }
        __syncthreads();
        if (tid < 64){
            float S = 0.f, S2 = 0.f;
#pragma unroll
            for (int w2 = 0; w2 < 4; w2++){
                S  += sred[w2*64 + tid];
                S2 += sred[256 + w2*64 + tid];
            }
            long i = (long)b*256 + tile;
            long off = (i*KOUT + bz*64 + tid)*2;
            part[off]   = S;
            part[off+1] = S2;
        }
        __syncthreads();
    }

    // ---- epilogue: LDS transpose -> NHWC bf16 raw (64-ch slice) ----
    {
        u16* ep = (u16*)smem;
#pragma unroll
        for (int m = 0; m < 4; m++)
#pragma unroll
            for (int n = 0; n < 4; n++){
                int ch = n*16 + (lane & 15);
#pragma unroll
                for (int j = 0; j < 4; j++){
                    int px = (w*4 + m)*16 + (lane>>4)*4 + j;
                    ep[px*64 + ch] = f2bf(acc[m][n][j]);
                }
            }
        __syncthreads();
        u16* outh = (u16*)out_;
        if (SPLIT && b >= 6) outh = rawhi - RAW_SPLIT;
#pragma unroll
        for (int it = 0; it < 8; ++it){
            int i = it*256 + tid;
            int px = i >> 3, u = i & 7;
            int py = px >> 4, pxc = px & 15;
            long ga = (pixbase + ((ty0+py)<<8) + tx0 + pxc) * KOUT + bz*64 + (long)u*8;
            *(int4*)(outh + ga) = *(int4*)(ep + (long)i*8);
        }
    }
}

// ---------------------------------------------------------------------------
// conv1: 3->32 direct (tiny), output NHWC bf16 raw
// ---------------------------------------------------------------------------
__global__ __launch_bounds__(256)
void conv1_direct(const float* __restrict__ x, const float* __restrict__ w1, u16* __restrict__ f1)
{
    __shared__ float wl[864];
    const int t = threadIdx.x;
    for (int i = t; i < 864; i += 256) wl[i] = w1[i];
    __syncthreads();
    const int y = blockIdx.x, b = blockIdx.y;
    float acc[32];
#pragma unroll
    for (int k = 0; k < 32; k++) acc[k] = 0.f;
    const long ib = (long)b*3*65536;
    for (int c = 0; c < 3; c++){
#pragma unroll
        for (int dy = 0; dy < 3; dy++){
            int gy = y + dy - 1;
#pragma unroll
            for (int dx = 0; dx < 3; dx++){
                int gx = t + dx - 1;
                float v = 0.f;
                if ((unsigned)gy < 256u && (unsigned)gx < 256u)
                    v = x[ib + c*65536 + (gy<<8) + gx];
                const float* wp = &wl[c*9 + dy*3 + dx];
#pragma unroll
                for (int k = 0; k < 32; k++) acc[k] += v * wp[k*27];
            }
        }
    }
    u16 ub[32];
#pragma unroll
    for (int k = 0; k < 32; k++) ub[k] = f2bf(acc[k]);
    u16* dst = f1 + ((long)(b*65536 + (y<<8) + t)) * 32;
#pragma unroll
    for (int j = 0; j < 4; j++) *(int4*)(dst + j*8) = *(int4*)(ub + j*8);
}

// weight transpose: wt[tap][k][c] = bf16(w[k][c][tap])
__global__ __launch_bounds__(256)
void prep_w(const float* __restrict__ w, u16* __restrict__ wt, int K, int C)
{
    int i = blockIdx.x*256 + threadIdx.x;
    if (i >= 9*K*C) return;
    int c = i % C; int r = i / C; int k = r % K; int tap = r / K;
    wt[i] = f2bf(w[((long)k*C + c)*9 + tap]);
}

// ---------------------------------------------------------------------------
// BN stats over NHWC bf16 (layer 1 only)
// ---------------------------------------------------------------------------
template<int C>
__global__ __launch_bounds__(256)
void bn_stats_nhwc(const u16* __restrict__ f, float* __restrict__ part)
{
    constexpr int CQ = C/4;
    constexpr int SUBS = 256/CQ;
    const int t = threadIdx.x;
    const int cq = t & (CQ-1);
    const int sub = t / CQ;
    const long rowbase = (long)blockIdx.x * 512;
    float s[4] = {0,0,0,0}, q2[4] = {0,0,0,0};
    for (int r = sub; r < 512; r += SUBS){
        ushort4 v = *(const ushort4*)(f + (rowbase + r)*C + cq*4);
        float x0 = bf2f(v.x), x1 = bf2f(v.y), x2 = bf2f(v.z), x3 = bf2f(v.w);
        s[0]+=x0; q2[0]+=x0*x0; s[1]+=x1; q2[1]+=x1*x1;
        s[2]+=x2; q2[2]+=x2*x2; s[3]+=x3; q2[3]+=x3*x3;
    }
    __shared__ float r0[256], r1[256];
    for (int j = 0; j < 4; j++){
        r0[t] = s[j]; r1[t] = q2[j];
        __syncthreads();
        for (int st = 128; st >= CQ; st >>= 1){
            if (t < st){ r0[t] += r0[t+st]; r1[t] += r1[t+st]; }
            __syncthreads();
        }
        if (t < CQ){
            part[((long)blockIdx.x * C + t*4 + j)*2]     = r0[t];
            part[((long)blockIdx.x * C + t*4 + j)*2 + 1] = r1[t];
        }
        __syncthreads();
    }
}

__global__ __launch_bounds__(256)
void bn_stats_final2(const float* __restrict__ part, const float* __restrict__ g,
                     const float* __restrict__ bb, int C, int NB2, float* __restrict__ ss)
{
    const int c = blockIdx.x, t = threadIdx.x;
    float s = 0.f, s2 = 0.f;
    for (int i = t; i < NB2; i += 256){
        s  += part[((long)i*C + c)*2];
        s2 += part[((long)i*C + c)*2 + 1];
    }
    __shared__ float r0[256], r1[256];
    r0[t] = s; r1[t] = s2;
    __syncthreads();
    for (int st = 128; st > 0; st >>= 1){
        if (t < st){ r0[t] += r0[t+st]; r1[t] += r1[t+st]; }
        __syncthreads();
    }
    if (t == 0){
        const float invN = 1.f/524288.f;
        float m = r0[0]*invN;
        float v = r1[0]*invN - m*m;
        float sc = g[c]/sqrtf(v + 1e-5f);
        ss[c] = sc; ss[C+c] = bb[c] - m*sc;
    }
}

// ---------------------------------------------------------------------------
// f4 raw NHWC bf16 -> NCHW fp32 feat with BN+lrelu (LDS-tiled transpose).
// 64-px strip per block; 16 consecutive lanes write 16 consecutive float4s
// (256B contiguous) of one channel.
// ---------------------------------------------------------------------------
__global__ __launch_bounds__(256)
void bn_expand_t(const u16* __restrict__ rawlo, const u16* __restrict__ rawhi,
                 const float* __restrict__ ss, float* __restrict__ feat, int b0)
{
    __shared__ u16 lds[64*258];
    const int bid = blockIdx.x;
    const int b = b0 + (bid >> 10);
    const int px0 = (bid & 1023) * 64;
    const long p0 = (((long)(b<<16) + px0)) << 8;
    const u16* src = (b < 6) ? (rawlo + p0) : (rawhi + (p0 - RAW_SPLIT));
    const int t = threadIdx.x;
#pragma unroll
    for (int it = 0; it < 8; ++it){
        int i = it*256 + t;
        int px = i >> 5, u = i & 31;
        *(u16x8*)&lds[px*258 + u*8] = *(const u16x8*)(src + (long)i*8);
    }
    __syncthreads();
#pragma unroll
    for (int it = 0; it < 16; ++it){
        int idx = it*256 + t;
        int ch = idx >> 4;
        int q  = idx & 15;
        const float sc = ss[ch], sh = ss[256 + ch];
        float4 o;
        o.x = lrelu(sc*bf2f(lds[(q*4+0)*258 + ch]) + sh);
        o.y = lrelu(sc*bf2f(lds[(q*4+1)*258 + ch]) + sh);
        o.z = lrelu(sc*bf2f(lds[(q*4+2)*258 + ch]) + sh);
        o.w = lrelu(sc*bf2f(lds[(q*4+3)*258 + ch]) + sh);
        *(float4*)(feat + (((long)(b*256 + ch)) << 16) + px0 + q*4) = o;
    }
}

// ---------------------------------------------------------------------------
// gather W from raw NHWC bf16 + inline BN (matches bn_expand_t arithmetic)
// ---------------------------------------------------------------------------
__global__ __launch_bounds__(256)
void gather_w_raw(const u16* __restrict__ rawlo, const u16* __restrict__ rawhi,
                  const float* __restrict__ ss, const int* __restrict__ hw,
                  float* __restrict__ outW)
{
    const int site = blockIdx.x;
    const int b = site >> 10;
    const int y = hw[site*2], x = hw[site*2 + 1];
    const int c = threadIdx.x;
    const long p = ((long)((b<<16) + (y<<8) + x)) << 8;
    const u16* base = (b < 6) ? (rawlo + p) : (rawhi + (p - RAW_SPLIT));
    float v = bf2f(base[c]);
    outW[(long)site*256 + c] = lrelu(ss[c]*v + ss[256 + c]);
}

__global__ __launch_bounds__(256)
void gather_patch(const float* __restrict__ x, const int* __restrict__ hw,
                  float* __restrict__ out)
{
    const long i = (long)blockIdx.x*256 + threadIdx.x;
    if (i >= 1204224L) return;
    const int px = (int)(i % 7);
    long r = i / 7;
    const int py = (int)(r % 7); r /= 7;
    const int c  = (int)(r % 3); r /= 3;
    const int s  = (int)(r % 1024);
    const int b  = (int)(r / 1024);
    const int site = b*1024 + s;
    const int yy = hw[site*2]     - 3 + py;
    const int xx = hw[site*2 + 1] - 3 + px;
    out[i] = x[(((long)(b*3 + c)) << 16) + ((long)yy << 8) + xx];
}

// ---------------------------------------------------------------------------
// decoder MLP, 8 sites per block (8x weight reuse per load)
// ---------------------------------------------------------------------------
__global__ __launch_bounds__(256)
void mlp8(const float* __restrict__ Wa, const float* __restrict__ l1w,
          const float* __restrict__ l1b, const float* __restrict__ l2w,
          const float* __restrict__ l2b, float* __restrict__ out)
{
    __shared__ float wa[2048];
    __shared__ float h[8][152];
    const int blk = blockIdx.x;
    const int t = threadIdx.x;
#pragma unroll
    for (int it = 0; it < 8; ++it)
        wa[it*256 + t] = Wa[(long)blk*2048 + it*256 + t];
    __syncthreads();
    if (t < PD){
        float a[8] = {0,0,0,0,0,0,0,0};
        const float* wr = l1w + t*256;
#pragma unroll 4
        for (int l = 0; l < 256; ++l){
            float wv = wr[l];
#pragma unroll
            for (int g = 0; g < 8; ++g) a[g] += wa[g*256 + l]*wv;
        }
        float bb = l1b[t];
#pragma unroll
        for (int g = 0; g < 8; ++g) h[g][t] = lrelu(a[g] + bb);
    }
    __syncthreads();
    if (t < PD){
        float r[8] = {0,0,0,0,0,0,0,0};
        const float* wr = l2w + t*PD;
        for (int p = 0; p < PD; ++p){
            float wv = wr[p];
#pragma unroll
            for (int g = 0; g < 8; ++g) r[g] += h[g][p]*wv;
        }
        float bb = l2b[t];
#pragma unroll
        for (int g = 0; g < 8; ++g)
            out[((long)(blk*8 + g))*PD + t] = r[g] + bb;
    }
}

extern "C" void kernel_launch(void* const* d_in, const int* in_sizes, int n_in,
                              void* d_out, int out_size, void* d_ws, size_t ws_size,
                              hipStream_t stream)
{
    const float* x   = (const float*)d_in[0];
    const int*   anc = (const int*)  d_in[1];
    const int*   pos = (const int*)  d_in[2];
    const float* w1  = (const float*)d_in[3];
    const float* g1  = (const float*)d_in[4];
    const float* b1  = (const float*)d_in[5];
    const float* w2  = (const float*)d_in[6];
    const float* g2  = (const float*)d_in[7];
    const float* b2  = (const float*)d_in[8];
    const float* w3  = (const float*)d_in[9];
    const float* g3  = (const float*)d_in[10];
    const float* b3  = (const float*)d_in[11];
    const float* w4  = (const float*)d_in[12];
    const float* g4  = (const float*)d_in[13];
    const float* b4  = (const float*)d_in[14];
    const float* l1w = (const float*)d_in[15];
    const float* l1b = (const float*)d_in[16];
    const float* l2w = (const float*)d_in[17];
    const float* l2b = (const float*)d_in[18];

    float* feat = (float*)d_out;
    float* oPR  = feat + OFF_PREAL;
    float* oRC  = feat + OFF_PRECON;
    float* oWA  = feat + OFF_WA;
    float* oWP  = feat + OFF_WP;

    // ws: f2 [0,64MB), f3 [64MB,192MB), f1 [128MB,160MB) (inside f3, dead before conv3)
    char* wsb = (char*)d_ws;
    u16* f2b = (u16*)wsb;
    u16* f3b = (u16*)(wsb + 67108864L);
    u16* f1b = (u16*)(wsb + 134217728L);

    // raw f4 bf16 NHWC: batches 0..5 in top of feat region; 6,7 in f2 region
    u16* rawlo = (u16*)d_out + 167772160L;    // byte offset 335544320
    u16* rawhi = f2b;                          // f2 dead after conv3

    // scratch inside d_out regions only written by later kernels
    u16* Wt2 = (u16*)oWA;                      // dead after conv2
    u16* Wt3 = Wt2 + 18432;                    // dead after conv3
    u16* Wt4 = Wt3 + 73728;                    // dead after conv4
    float* part = oWP;                         // 2048*256*2 floats max = 4MB
    float* ss1 = oRC, *ss2 = oRC + 64, *ss3 = oRC + 192, *ss4 = oRC + 448;  // dead before mlp8

    prep_w<<<72,   256, 0, stream>>>(w2, Wt2, 64, 32);
    prep_w<<<288,  256, 0, stream>>>(w3, Wt3, 128, 64);
    prep_w<<<1152, 256, 0, stream>>>(w4, Wt4, 256, 128);

    // conv1 -> raw f1; stats on raw f1 -> ss1 (conv2 folds BN into A-staging)
    conv1_direct<<<dim3(256,8), 256, 0, stream>>>(x, w1, f1b);
    bn_stats_nhwc<32><<<1024, 256, 0, stream>>>(f1b, part);
    bn_stats_final2<<<32, 256, 0, stream>>>(part, g1, b1, 32, 1024, ss1);

    conv_mfma<32,64,false><<<dim3(256,1,8), 256, 0, stream>>>(f1b, Wt2, ss1, f2b, nullptr, part);
    bn_stats_final2<<<64, 256, 0, stream>>>(part, g2, b2, 64, 2048, ss2);

    conv_mfma<64,128,false><<<dim3(256,2,8), 256, 0, stream>>>(f2b, Wt3, ss2, f3b, nullptr, part);
    bn_stats_final2<<<128, 256, 0, stream>>>(part, g3, b3, 128, 2048, ss3);

    conv_mfma<128,256,true><<<dim3(256,4,8), 256, 0, stream>>>(f3b, Wt4, ss3, rawlo, rawhi, part);
    bn_stats_final2<<<256, 256, 0, stream>>>(part, g4, b4, 256, 2048, ss4);

    // gathers read RAW f4 (+inline BN) BEFORE the expand kernels clobber raw
    gather_w_raw<<<8192, 256, 0, stream>>>(rawlo, rawhi, ss4, anc, oWA);
    gather_w_raw<<<8192, 256, 0, stream>>>(rawlo, rawhi, ss4, pos, oWP);
    gather_patch<<<4704, 256, 0, stream>>>(x, anc, oPR);

    // expand raw -> fp32 feat (transpose).  Safety by launch order:
    //  E1: b 0..4  writes feat bytes [0, 335.5MB)       (below rawlo)
    //  E2: b 5     writes [335.5, 402.7) = raw of b0,b1 (read by E1)
    //  E3: b 6,7   reads ws, writes [402.7, 537) = raw of b2..b5 (read E1/E2)
    bn_expand_t<<<5120, 256, 0, stream>>>(rawlo, rawhi, ss4, feat, 0);
    bn_expand_t<<<1024, 256, 0, stream>>>(rawlo, rawhi, ss4, feat, 5);
    bn_expand_t<<<2048, 256, 0, stream>>>(rawlo, rawhi, ss4, feat, 6);

    // mlp last: it overwrites oRC (incl. ss slots) after all consumers done
    mlp8<<<1024, 256, 0, stream>>>(oWA, l1w, l1b, l2w, l2b, oRC);
}